// Round 7
// baseline (1468.326 us; speedup 1.0000x reference)
//
#include <hip/hip_runtime.h>
#include <hip/hip_bf16.h>
#include <cstdio>
#include <cstring>

#define FIN 6
#define HC 64
#define LAYERS 3

// monotone float -> uint map (order-preserving), for atomicMax on signed floats
static __device__ __forceinline__ unsigned int fenc(float f) {
  unsigned int u = __float_as_uint(f);
  return (u & 0x80000000u) ? ~u : (u | 0x80000000u);
}
static __device__ __forceinline__ float fdec(unsigned int u) {
  return __uint_as_float((u & 0x80000000u) ? (u & 0x7FFFFFFFu) : ~u);
}
#define AGG_INIT 0x007FFFFFu  // fenc(-inf)

__global__ void PathfindingGNN_17274358464713_kernel() {}

// ---------------- encoder: h0 = x @ W_enc + b_enc ----------------
__global__ __launch_bounds__(256) void k_encode(const float* __restrict__ x,
                                                const float* __restrict__ W,
                                                const float* __restrict__ b,
                                                float* __restrict__ h, int Nn) {
  int idx = blockIdx.x * 256 + threadIdx.x;
  if (idx >= Nn * HC) return;
  int n = idx >> 6, c = idx & 63;
  float s = b[c];
#pragma unroll
  for (int f = 0; f < FIN; ++f)
    s = fmaf(x[n * FIN + f], W[f * HC + c], s);
  h[idx] = s;
}

// ---------------- aggregate: init / per-(edge,channel) atomicMax / finalize ----------------
__global__ __launch_bounds__(256) void k_agg_init(unsigned int* __restrict__ aggU, int total) {
  int i = blockIdx.x * 256 + threadIdx.x;
  if (i < total) aggU[i] = AGG_INIT;
}

__global__ __launch_bounds__(256) void k_agg_edges(const float* __restrict__ h,
                                                   const int* __restrict__ src,
                                                   const int* __restrict__ dst,
                                                   const float* __restrict__ ea,
                                                   const float* __restrict__ We,
                                                   const float* __restrict__ be,
                                                   unsigned int* __restrict__ aggU, int E) {
  int gid = blockIdx.x * 256 + threadIdx.x;
  int e = gid >> 6, c = gid & 63;
  if (e >= E) return;
  int s = src[e], d = dst[e];
  float ef = fmaf(ea[e], We[c], be[c]);
  float m = h[s * HC + c] * ef;
  atomicMax(&aggU[d * HC + c], fenc(m));
}

__global__ __launch_bounds__(256) void k_agg_fin(unsigned int* __restrict__ aggU,
                                                 float* __restrict__ aggF, int total) {
  int i = blockIdx.x * 256 + threadIdx.x;
  if (i >= total) return;
  unsigned int u = aggU[i];
  aggF[i] = (u == AGG_INIT) ? 0.0f : fdec(u);
}

// ---------------- update: relu(BN(relu(cat[h,agg] @ W + b))) ----------------
__global__ __launch_bounds__(256) void k_update(const float* __restrict__ h,
                                                const float* __restrict__ agg,
                                                const float* __restrict__ W,
                                                const float* __restrict__ b,
                                                const float* __restrict__ gam, const float* __restrict__ bet,
                                                const float* __restrict__ mean, const float* __restrict__ var,
                                                float* __restrict__ out, int Nn) {
  int idx = blockIdx.x * 256 + threadIdx.x;
  if (idx >= Nn * HC) return;
  int n = idx >> 6, c = idx & 63;
  float s = b[c];
#pragma unroll 8
  for (int k = 0; k < HC; ++k)
    s = fmaf(h[n * HC + k], W[k * HC + c], s);
#pragma unroll 8
  for (int k = 0; k < HC; ++k)
    s = fmaf(agg[n * HC + k], W[(HC + k) * HC + c], s);
  s = fmaxf(s, 0.0f);
  s = fmaxf((s - mean[c]) * (gam[c] * rsqrtf(var[c] + 1e-5f)) + bet[c], 0.0f);
  out[idx] = s;
}

// ---------------- predictor part 1: t = relu(h @ Wp1 + b1) ----------------
__global__ __launch_bounds__(256) void k_mlp1(const float* __restrict__ h,
                                              const float* __restrict__ Wp1,
                                              const float* __restrict__ bp1,
                                              float* __restrict__ t, int Nn) {
  int idx = blockIdx.x * 256 + threadIdx.x;
  if (idx >= Nn * HC) return;
  int n = idx >> 6, j = idx & 63;
  float s = bp1[j];
#pragma unroll 8
  for (int k = 0; k < HC; ++k)
    s = fmaf(h[n * HC + k], Wp1[k * HC + j], s);
  t[idx] = fmaxf(s, 0.0f);
}

// ---------------- predictor part 2: out = t @ Wp2 + b2 ----------------
__global__ __launch_bounds__(256) void k_mlp2(const float* __restrict__ t,
                                              const float* __restrict__ Wp2,
                                              const float* __restrict__ bp2,
                                              float* __restrict__ out, int Nn) {
  int n = blockIdx.x * 256 + threadIdx.x;
  if (n >= Nn) return;
  float s = bp2[0];
#pragma unroll 8
  for (int j = 0; j < HC; ++j)
    s = fmaf(t[n * HC + j], Wp2[j], s);
  out[n] = s;
}

extern "C" void kernel_launch(void* const* d_in, const int* in_sizes, int n_in,
                              void* d_out, int out_size, void* d_ws, size_t ws_size,
                              hipStream_t stream) {
  const float* x = (const float*)d_in[0];
  const int* eidx = (const int*)d_in[1];
  const float* eattr = (const float*)d_in[2];
  const float* Wenc = (const float*)d_in[3];
  const float* benc = (const float*)d_in[4];
  const float* Wedge = (const float*)d_in[5];
  const float* bedge = (const float*)d_in[6];
  const float* Wupd = (const float*)d_in[7];
  const float* bupd = (const float*)d_in[8];
  const float* bng = (const float*)d_in[9];
  const float* bnb = (const float*)d_in[10];
  const float* bnm = (const float*)d_in[11];
  const float* bnv = (const float*)d_in[12];
  const float* Wp1 = (const float*)d_in[13];
  const float* bp1 = (const float*)d_in[14];
  const float* Wp2 = (const float*)d_in[15];
  const float* bp2 = (const float*)d_in[16];

  const int Nn = in_sizes[0] / FIN;
  const int E = in_sizes[1] / 2;
  const int* src = eidx;
  const int* dst = eidx + E;
  const int NH = Nn * HC;

  size_t off = 0;
  char* base = (char*)d_ws;
  auto carve = [&](size_t bytes) -> void* {
    void* p = base + off;
    off += (bytes + 255) & ~(size_t)255;
    return p;
  };
  float* h0 = (float*)carve((size_t)NH * 4);
  float* h1 = (float*)carve((size_t)NH * 4);
  float* h2 = (float*)carve((size_t)NH * 4);
  float* h3 = (float*)carve((size_t)NH * 4);
  unsigned int* aggU = (unsigned int*)carve((size_t)NH * 4);
  float* aggF = (float*)aggU;  // decoded in place
  float* tbuf = (float*)carve((size_t)NH * 4);
  if (off > ws_size) {
    fprintf(stderr, "[DIAG] WS too small %zu > %zu\n", off, ws_size);
    return;
  }

  int nhB = (NH + 255) / 256;
  int ecB = ((E * HC) + 255) / 256;  // one thread per (edge, channel)
  int nB = (Nn + 255) / 256;

  k_encode<<<nhB, 256, 0, stream>>>(x, Wenc, benc, h0, Nn);
  float* hs[4] = {h0, h1, h2, h3};
  for (int i = 0; i < LAYERS; ++i) {
    k_agg_init<<<nhB, 256, 0, stream>>>(aggU, NH);
    k_agg_edges<<<ecB, 256, 0, stream>>>(hs[i], src, dst, eattr,
                                         Wedge + i * HC, bedge + i * HC, aggU, E);
    k_agg_fin<<<nhB, 256, 0, stream>>>(aggU, aggF, NH);
    k_update<<<nhB, 256, 0, stream>>>(hs[i], aggF, Wupd + i * 2 * HC * HC, bupd + i * HC,
                                      bng + i * HC, bnb + i * HC, bnm + i * HC, bnv + i * HC,
                                      hs[i + 1], Nn);
  }
  k_mlp1<<<nhB, 256, 0, stream>>>(h3, Wp1, bp1, tbuf, Nn);
  k_mlp2<<<nB, 256, 0, stream>>>(tbuf, Wp2, bp2, (float*)d_out, Nn);

  hipError_t e1 = hipGetLastError();

  // ---------------- same-call forensics (correctness call only, never during capture) ----
  hipStreamCaptureStatus cs = hipStreamCaptureStatusNone;
  hipStreamIsCapturing(stream, &cs);
  if (cs != hipStreamCaptureStatusNone) return;

  static float hx[FIN * 2];
  static float hW[FIN * HC];
  static float hbc[HC];
  static float hh0[8], hh3[8], ht[8], hout[8];
  hipMemcpyAsync(hx, d_in[0], sizeof(hx), hipMemcpyDeviceToHost, stream);
  hipMemcpyAsync(hW, d_in[3], sizeof(hW), hipMemcpyDeviceToHost, stream);
  hipMemcpyAsync(hbc, d_in[4], sizeof(hbc), hipMemcpyDeviceToHost, stream);
  hipMemcpyAsync(hh0, h0, sizeof(hh0), hipMemcpyDeviceToHost, stream);
  hipMemcpyAsync(hh3, h3, sizeof(hh3), hipMemcpyDeviceToHost, stream);
  hipMemcpyAsync(ht, tbuf, sizeof(ht), hipMemcpyDeviceToHost, stream);
  hipMemcpyAsync(hout, d_out, sizeof(hout), hipMemcpyDeviceToHost, stream);
  hipError_t esync = hipStreamSynchronize(stream);

  float expct[4];
  for (int c = 0; c < 4; ++c) {
    float s = hbc[c];
    for (int f = 0; f < FIN; ++f) s += hx[f] * hW[f * HC + c];
    expct[c] = s;
  }
  fprintf(stderr, "[F] enq=%d sync=%d | x: %.4f %.4f %.4f %.4f\n",
          (int)e1, (int)esync, hx[0], hx[1], hx[2], hx[3]);
  fprintf(stderr, "[F] h0 gpu: %.6f %.6f %.6f %.6f | cpu: %.6f %.6f %.6f %.6f\n",
          hh0[0], hh0[1], hh0[2], hh0[3], expct[0], expct[1], expct[2], expct[3]);
  fprintf(stderr, "[F] h3: %.6f %.6f  t: %.6f %.6f  out: %.6f %.6f %.6f %.6f\n",
          hh3[0], hh3[1], ht[0], ht[1], hout[0], hout[1], hout[2], hout[3]);
}

// Round 8
// 761.834 us; speedup vs baseline: 1.9274x; 1.9274x over previous
//
#include <hip/hip_runtime.h>
#include <cstdio>

#define FIN 6
#define HC 64
#define LAYERS 3

__global__ void PathfindingGNN_17274358464713_kernel() {}

__global__ __launch_bounds__(256) void k_zero(int* __restrict__ p, int n) {
  int i = blockIdx.x * 256 + threadIdx.x;
  if (i < n) p[i] = 0;
}

// ---------------- encoder: h0 = x @ W_enc + b_enc ----------------
__global__ __launch_bounds__(256) void k_encode(const float* __restrict__ x,
                                                const float* __restrict__ W,
                                                const float* __restrict__ b,
                                                float* __restrict__ h, int Nn) {
  int idx = blockIdx.x * 256 + threadIdx.x;
  if (idx >= Nn * HC) return;
  int n = idx >> 6, c = idx & 63;
  float s = b[c];
#pragma unroll
  for (int f = 0; f < FIN; ++f)
    s = fmaf(x[n * FIN + f], W[f * HC + c], s);
  h[idx] = s;
}

// ---------------- CSR build ----------------
__global__ __launch_bounds__(256) void k_hist(const int* __restrict__ dst, int* __restrict__ counts, int E) {
  int e = blockIdx.x * 256 + threadIdx.x;
  if (e < E) atomicAdd(&counts[dst[e]], 1);
}

__global__ __launch_bounds__(256) void k_scan1(const int* __restrict__ counts, int* __restrict__ partial,
                                               int* __restrict__ blockSums, int n) {
  __shared__ int lds[256];
  int tid = threadIdx.x;
  int base = blockIdx.x * 2048 + tid * 8;
  int v[8], e[8], s = 0;
#pragma unroll
  for (int j = 0; j < 8; ++j) {
    v[j] = (base + j < n) ? counts[base + j] : 0;
    e[j] = s;
    s += v[j];
  }
  lds[tid] = s;
  __syncthreads();
  for (int d = 1; d < 256; d <<= 1) {
    int t = (tid >= d) ? lds[tid - d] : 0;
    __syncthreads();
    lds[tid] += t;
    __syncthreads();
  }
  int off = (tid == 0) ? 0 : lds[tid - 1];
#pragma unroll
  for (int j = 0; j < 8; ++j)
    if (base + j < n) partial[base + j] = off + e[j];
  if (tid == 0) blockSums[blockIdx.x] = lds[255];
}

__global__ __launch_bounds__(256) void k_scan2(const int* __restrict__ blockSums, int* __restrict__ blockOff, int nb) {
  __shared__ int lds[256];
  int tid = threadIdx.x;
  lds[tid] = (tid < nb) ? blockSums[tid] : 0;
  __syncthreads();
  for (int d = 1; d < 256; d <<= 1) {
    int t = (tid >= d) ? lds[tid - d] : 0;
    __syncthreads();
    lds[tid] += t;
    __syncthreads();
  }
  if (tid < nb) blockOff[tid] = (tid == 0) ? 0 : lds[tid - 1];
}

__global__ __launch_bounds__(256) void k_scan3(int* __restrict__ rp, const int* __restrict__ boff,
                                               int* __restrict__ cursor, int n, int total) {
  int i = blockIdx.x * 256 + threadIdx.x;
  if (i > n) return;
  int v = (i == n) ? total : rp[i] + boff[i >> 11];
  rp[i] = v;
  cursor[i] = v;
}

__global__ __launch_bounds__(256) void k_scatter(const int* __restrict__ src, const int* __restrict__ dst,
                                                 const float* __restrict__ ea, int* __restrict__ cursor,
                                                 int* __restrict__ csr_src, float* __restrict__ csr_ea, int E) {
  int e = blockIdx.x * 256 + threadIdx.x;
  if (e >= E) return;
  int d = dst[e];
  int p = atomicAdd(&cursor[d], 1);
  csr_src[p] = src[e];
  csr_ea[p] = ea[e];
}

// ---------------- fused layer: CSR aggregate-max (LDS) + update GEMM + BN ----------------
// 64 nodes/block, 256 threads. LDS: Asm 17,408B + Wsm 16,384B = 33,792B -> 4 blocks/CU.
// Phase 0: Asm = agg (gather-max), GEMM vs W rows 64..127 (agg half of concat).
// Phase 1: Asm = h(self), GEMM vs W rows 0..63. Sum order irrelevant.
__global__ __launch_bounds__(256) void k_layer(const float* __restrict__ h, const int* __restrict__ row_ptr,
                                               const int* __restrict__ csr_src, const float* __restrict__ csr_ea,
                                               const float* __restrict__ We, const float* __restrict__ be,
                                               const float* __restrict__ W, const float* __restrict__ b,
                                               const float* __restrict__ gam, const float* __restrict__ bet,
                                               const float* __restrict__ mean, const float* __restrict__ var,
                                               float* __restrict__ out, int Nn) {
  __shared__ float Asm[64][68];
  __shared__ float Wsm[64][64];
  int tid = threadIdx.x;
  int nb = blockIdx.x * 64;
  int c = tid & 63, w = tid >> 6;

  // stage W rows 64..127 (multiplies agg)
  for (int i = tid; i < 64 * 64; i += 256) Wsm[i >> 6][i & 63] = W[64 * 64 + i];

  // aggregate: each wave handles 16 nodes, lane = channel; dual chain for latency
  float we = We[c], bev = be[c];
  for (int i = 0; i < 16; ++i) {
    int nl = w * 16 + i;
    int nc = min(nb + nl, Nn - 1);
    int r0 = row_ptr[nc], r1 = row_ptr[nc + 1];
    float m0 = -INFINITY, m1 = -INFINITY;
    int r = r0;
    for (; r + 1 < r1; r += 2) {
      int s0 = csr_src[r], s1 = csr_src[r + 1];
      float a0 = csr_ea[r], a1 = csr_ea[r + 1];
      float h0 = h[s0 * HC + c], h1 = h[s1 * HC + c];
      m0 = fmaxf(m0, h0 * fmaf(a0, we, bev));
      m1 = fmaxf(m1, h1 * fmaf(a1, we, bev));
    }
    if (r < r1) {
      int s0 = csr_src[r];
      float a0 = csr_ea[r];
      m0 = fmaxf(m0, h[s0 * HC + c] * fmaf(a0, we, bev));
    }
    float m = fmaxf(m0, m1);
    Asm[nl][c] = (m == -INFINITY) ? 0.0f : m;  // empty segment -> 0
  }
  __syncthreads();

  int c0 = (tid & 15) * 4, n0 = (tid >> 4) * 4;
  float acc[4][4] = {{0.f}};
#pragma unroll 4
  for (int k = 0; k < 64; k += 4) {
    float a[4][4], wv[4][4];
#pragma unroll
    for (int j = 0; j < 4; ++j) {
      float4 t = *(const float4*)&Asm[n0 + j][k];
      a[j][0] = t.x; a[j][1] = t.y; a[j][2] = t.z; a[j][3] = t.w;
    }
#pragma unroll
    for (int j = 0; j < 4; ++j) {
      float4 t = *(const float4*)&Wsm[k + j][c0];
      wv[j][0] = t.x; wv[j][1] = t.y; wv[j][2] = t.z; wv[j][3] = t.w;
    }
#pragma unroll
    for (int i = 0; i < 4; ++i)
#pragma unroll
      for (int j = 0; j < 4; ++j)
#pragma unroll
        for (int l = 0; l < 4; ++l)
          acc[i][l] = fmaf(a[i][j], wv[j][l], acc[i][l]);
  }
  __syncthreads();

  // phase 1: restage with h(self) and W rows 0..63
  for (int i = tid; i < 64 * 64; i += 256) Wsm[i >> 6][i & 63] = W[i];
#pragma unroll
  for (int i = 0; i < 16; ++i) {
    int nl = i * 4 + w;
    int ng = min(nb + nl, Nn - 1);
    Asm[nl][c] = h[ng * HC + c];
  }
  __syncthreads();
#pragma unroll 4
  for (int k = 0; k < 64; k += 4) {
    float a[4][4], wv[4][4];
#pragma unroll
    for (int j = 0; j < 4; ++j) {
      float4 t = *(const float4*)&Asm[n0 + j][k];
      a[j][0] = t.x; a[j][1] = t.y; a[j][2] = t.z; a[j][3] = t.w;
    }
#pragma unroll
    for (int j = 0; j < 4; ++j) {
      float4 t = *(const float4*)&Wsm[k + j][c0];
      wv[j][0] = t.x; wv[j][1] = t.y; wv[j][2] = t.z; wv[j][3] = t.w;
    }
#pragma unroll
    for (int i = 0; i < 4; ++i)
#pragma unroll
      for (int j = 0; j < 4; ++j)
#pragma unroll
        for (int l = 0; l < 4; ++l)
          acc[i][l] = fmaf(a[i][j], wv[j][l], acc[i][l]);
  }

  float scale[4], shift[4], bias[4];
#pragma unroll
  for (int l = 0; l < 4; ++l) {
    int cc = c0 + l;
    bias[l] = b[cc];
    float sc = gam[cc] * rsqrtf(var[cc] + 1e-5f);
    scale[l] = sc;
    shift[l] = bet[cc] - mean[cc] * sc;
  }
#pragma unroll
  for (int i = 0; i < 4; ++i) {
    int n = nb + n0 + i;
    if (n < Nn) {
      float4 o;
      float v;
      v = fmaxf(acc[i][0] + bias[0], 0.f); o.x = fmaxf(fmaf(v, scale[0], shift[0]), 0.f);
      v = fmaxf(acc[i][1] + bias[1], 0.f); o.y = fmaxf(fmaf(v, scale[1], shift[1]), 0.f);
      v = fmaxf(acc[i][2] + bias[2], 0.f); o.z = fmaxf(fmaf(v, scale[2], shift[2]), 0.f);
      v = fmaxf(acc[i][3] + bias[3], 0.f); o.w = fmaxf(fmaf(v, scale[3], shift[3]), 0.f);
      *(float4*)&out[n * HC + c0] = o;
    }
  }
}

// ---------------- fused predictor: out = relu(h @ Wp1 + b1) @ Wp2 + b2 ----------------
__global__ __launch_bounds__(256) void k_predict(const float* __restrict__ h, const float* __restrict__ Wp1,
                                                 const float* __restrict__ bp1, const float* __restrict__ Wp2,
                                                 const float* __restrict__ bp2, float* __restrict__ out, int Nn) {
  __shared__ float Asm[64][68];
  __shared__ float Wsm[64][64];
  __shared__ float red[64][17];
  int tid = threadIdx.x;
  int nb = blockIdx.x * 64;
  for (int i = tid; i < 64 * 64; i += 256) Wsm[i >> 6][i & 63] = Wp1[i];
  int c = tid & 63, w = tid >> 6;
#pragma unroll
  for (int i = 0; i < 16; ++i) {
    int nl = i * 4 + w;
    int ng = min(nb + nl, Nn - 1);
    Asm[nl][c] = h[ng * HC + c];
  }
  __syncthreads();
  int c0 = (tid & 15) * 4, n0 = (tid >> 4) * 4;
  float acc[4][4] = {{0.f}};
#pragma unroll 4
  for (int k = 0; k < 64; k += 4) {
    float a[4][4], wv[4][4];
#pragma unroll
    for (int j = 0; j < 4; ++j) {
      float4 t = *(const float4*)&Asm[n0 + j][k];
      a[j][0] = t.x; a[j][1] = t.y; a[j][2] = t.z; a[j][3] = t.w;
    }
#pragma unroll
    for (int j = 0; j < 4; ++j) {
      float4 t = *(const float4*)&Wsm[k + j][c0];
      wv[j][0] = t.x; wv[j][1] = t.y; wv[j][2] = t.z; wv[j][3] = t.w;
    }
#pragma unroll
    for (int i = 0; i < 4; ++i)
#pragma unroll
      for (int j = 0; j < 4; ++j)
#pragma unroll
        for (int l = 0; l < 4; ++l)
          acc[i][l] = fmaf(a[i][j], wv[j][l], acc[i][l]);
  }
  float bias[4], w2[4];
#pragma unroll
  for (int l = 0; l < 4; ++l) {
    bias[l] = bp1[c0 + l];
    w2[l] = Wp2[c0 + l];
  }
#pragma unroll
  for (int i = 0; i < 4; ++i) {
    float s = 0.f;
#pragma unroll
    for (int l = 0; l < 4; ++l) {
      float t = fmaxf(acc[i][l] + bias[l], 0.f);
      s = fmaf(t, w2[l], s);
    }
    red[n0 + i][tid & 15] = s;
  }
  __syncthreads();
  if (tid < 64) {
    float s = bp2[0];
#pragma unroll
    for (int g = 0; g < 16; ++g) s += red[tid][g];
    int n = nb + tid;
    if (n < Nn) out[n] = s;
  }
}

extern "C" void kernel_launch(void* const* d_in, const int* in_sizes, int n_in,
                              void* d_out, int out_size, void* d_ws, size_t ws_size,
                              hipStream_t stream) {
  const float* x = (const float*)d_in[0];
  const int* eidx = (const int*)d_in[1];
  const float* eattr = (const float*)d_in[2];
  const float* Wenc = (const float*)d_in[3];
  const float* benc = (const float*)d_in[4];
  const float* Wedge = (const float*)d_in[5];
  const float* bedge = (const float*)d_in[6];
  const float* Wupd = (const float*)d_in[7];
  const float* bupd = (const float*)d_in[8];
  const float* bng = (const float*)d_in[9];
  const float* bnb = (const float*)d_in[10];
  const float* bnm = (const float*)d_in[11];
  const float* bnv = (const float*)d_in[12];
  const float* Wp1 = (const float*)d_in[13];
  const float* bp1 = (const float*)d_in[14];
  const float* Wp2 = (const float*)d_in[15];
  const float* bp2 = (const float*)d_in[16];

  const int Nn = in_sizes[0] / FIN;
  const int E = in_sizes[1] / 2;
  const int* src = eidx;
  const int* dst = eidx + E;
  const int NH = Nn * HC;

  size_t off = 0;
  char* base = (char*)d_ws;
  auto carve = [&](size_t bytes) -> void* {
    void* p = base + off;
    off += (bytes + 255) & ~(size_t)255;
    return p;
  };
  int* row_ptr = (int*)carve((size_t)(Nn + 1) * 4);
  int* cursor = (int*)carve((size_t)(Nn + 1) * 4);
  int* counts = (int*)carve((size_t)(Nn + 1) * 4);
  int* bsums = (int*)carve(256 * 4);
  int* boffs = (int*)carve(256 * 4);
  int* csr_src = (int*)carve((size_t)E * 4);
  float* csr_ea = (float*)carve((size_t)E * 4);
  float* hA = (float*)carve((size_t)NH * 4);
  float* hB = (float*)carve((size_t)NH * 4);
  if (off > ws_size) {
    fprintf(stderr, "[DIAG] WS too small %zu > %zu\n", off, ws_size);
    return;
  }

  int nhB = (NH + 255) / 256;
  int histB = (E + 255) / 256;
  int scan1B = (Nn + 2047) / 2048;
  int scan3B = (Nn + 1 + 255) / 256;
  int updB = (Nn + 63) / 64;

  k_zero<<<scan3B, 256, 0, stream>>>(counts, Nn + 1);
  k_encode<<<nhB, 256, 0, stream>>>(x, Wenc, benc, hA, Nn);
  k_hist<<<histB, 256, 0, stream>>>(dst, counts, E);
  k_scan1<<<scan1B, 256, 0, stream>>>(counts, row_ptr, bsums, Nn);
  k_scan2<<<1, 256, 0, stream>>>(bsums, boffs, scan1B);
  k_scan3<<<scan3B, 256, 0, stream>>>(row_ptr, boffs, cursor, Nn, E);
  k_scatter<<<histB, 256, 0, stream>>>(src, dst, eattr, cursor, csr_src, csr_ea, E);

  float* hc = hA;
  float* hn = hB;
  for (int i = 0; i < LAYERS; ++i) {
    k_layer<<<updB, 256, 0, stream>>>(hc, row_ptr, csr_src, csr_ea,
                                      Wedge + i * HC, bedge + i * HC,
                                      Wupd + i * 2 * HC * HC, bupd + i * HC,
                                      bng + i * HC, bnb + i * HC, bnm + i * HC, bnv + i * HC,
                                      hn, Nn);
    float* t = hc; hc = hn; hn = t;
  }
  k_predict<<<updB, 256, 0, stream>>>(hc, Wp1, bp1, Wp2, bp2, (float*)d_out, Nn);

  // minimal forensics on the non-captured correctness call only
  hipStreamCaptureStatus cs = hipStreamCaptureStatusNone;
  hipStreamIsCapturing(stream, &cs);
  if (cs != hipStreamCaptureStatusNone) return;
  static float hout[4];
  static int hrp[4];
  hipMemcpyAsync(hout, d_out, sizeof(hout), hipMemcpyDeviceToHost, stream);
  hipMemcpyAsync(hrp, row_ptr + Nn - 3, sizeof(hrp), hipMemcpyDeviceToHost, stream);
  hipStreamSynchronize(stream);
  fprintf(stderr, "[F] out: %.6f %.6f %.6f %.6f | row_ptr tail: %d %d %d %d (last should be %d)\n",
          hout[0], hout[1], hout[2], hout[3], hrp[0], hrp[1], hrp[2], hrp[3], E);
}